// Round 1
// baseline (19701.556 us; speedup 1.0000x reference)
//
#include <hip/hip_runtime.h>
#include <hip/hip_bf16.h>
#include <math.h>

#define B_SZ 128
#define T_SZ 2048
#define NI 512
#define NH 512

// ---------------------------------------------------------------------------
// Kernel 1: x_proj = inputs @ W_xh + b_h, written IN-PLACE into d_out's outs
// region. outs layout [B,T,NH] flat, row m = b*T + t == A's row index, so
// C[m][n] -> d_out[m*NH + n]. Classic fp32 tiled GEMM, 64x64 tile, 4x4/thread.
// ---------------------------------------------------------------------------
#define BM 64
#define BN 64
#define BK 16

__global__ __launch_bounds__(256) void proj_gemm(
    const float* __restrict__ A,      // inputs [M=B*T, K=NI]
    const float* __restrict__ W,      // W_xh [K, N]
    const float* __restrict__ bias,   // b_h [N]
    float* __restrict__ C)            // d_out outs region [M, N]
{
    __shared__ float As[BK][BM];
    __shared__ float Bs[BK][BN];
    const int m0 = blockIdx.y * BM;
    const int n0 = blockIdx.x * BN;
    const int tid = threadIdx.x;
    const int tx = tid & 15;        // 0..15 col micro-group
    const int ty = tid >> 4;        // 0..15 row micro-group

    // load-index decomposition
    const int ar = tid >> 2;        // 0..63: row within A tile
    const int ac = (tid & 3) * 4;   // 0,4,8,12: k offset (float4)
    const int bk = tid >> 4;        // 0..15: k row within B tile
    const int bn = (tid & 15) * 4;  // col offset (float4)

    float acc[4][4] = {};

    for (int k0 = 0; k0 < NI; k0 += BK) {
        float4 av = *reinterpret_cast<const float4*>(
            &A[(size_t)(m0 + ar) * NI + k0 + ac]);
        float4 bv = *reinterpret_cast<const float4*>(
            &W[(size_t)(k0 + bk) * NH + n0 + bn]);
        __syncthreads();  // previous iteration's LDS reads complete
        As[ac + 0][ar] = av.x;
        As[ac + 1][ar] = av.y;
        As[ac + 2][ar] = av.z;
        As[ac + 3][ar] = av.w;
        *reinterpret_cast<float4*>(&Bs[bk][bn]) = bv;
        __syncthreads();
        #pragma unroll
        for (int kk = 0; kk < BK; ++kk) {
            float a[4], b[4];
            #pragma unroll
            for (int i = 0; i < 4; ++i) a[i] = As[kk][ty * 4 + i];
            #pragma unroll
            for (int j = 0; j < 4; ++j) b[j] = Bs[kk][tx * 4 + j];
            #pragma unroll
            for (int i = 0; i < 4; ++i)
                #pragma unroll
                for (int j = 0; j < 4; ++j)
                    acc[i][j] = fmaf(a[i], b[j], acc[i][j]);
        }
    }

    #pragma unroll
    for (int i = 0; i < 4; ++i) {
        const size_t row = (size_t)(m0 + ty * 4 + i);
        #pragma unroll
        for (int j = 0; j < 4; ++j) {
            const int col = n0 + tx * 4 + j;
            C[row * NH + col] = acc[i][j] + bias[col];
        }
    }
}

// ---------------------------------------------------------------------------
// Kernel 2: sequential scan. One workgroup per batch chain (128 WGs, 512 thr).
// h kept double-buffered in LDS; W_hh streamed from L2 every step (1 MB/step,
// L2-resident since all 16 WGs/XCD read the same W). Thread j owns hidden
// unit j: reads xp from d_out (written by proj_gemm), overwrites with h_t.
// ---------------------------------------------------------------------------
__global__ __launch_bounds__(512) void rnn_scan(
    const float* __restrict__ W,    // W_hh [NH, NH] row-major
    const float* __restrict__ H0,   // [B, NH]
    float* __restrict__ out,        // [B, T, NH]: xp on entry, h_t on exit
    float* __restrict__ hT)         // [B, NH]
{
    __shared__ float h[2][NH];
    const int b = blockIdx.x;
    const int j = threadIdx.x;

    h[0][j] = H0[(size_t)b * NH + j];
    __syncthreads();

    float* outb = out + (size_t)b * T_SZ * NH;
    const float* wc = W + j;        // column j, stride NH
    int cur = 0;
    float hn = 0.0f;

    for (int t = 0; t < T_SZ; ++t) {
        float acc = outb[(size_t)t * NH + j];   // xp_t[b][j]
        const float* hc = h[cur];
        #pragma unroll 16
        for (int k = 0; k < NH; ++k) {
            acc = fmaf(hc[k], wc[(size_t)k * NH], acc);
        }
        hn = tanhf(acc);
        h[cur ^ 1][j] = hn;
        outb[(size_t)t * NH + j] = hn;
        cur ^= 1;
        __syncthreads();  // h[cur] fully written before next step reads it
    }

    hT[(size_t)b * NH + j] = hn;    // final hidden state
}

// ---------------------------------------------------------------------------
extern "C" void kernel_launch(void* const* d_in, const int* in_sizes, int n_in,
                              void* d_out, int out_size, void* d_ws, size_t ws_size,
                              hipStream_t stream) {
    const float* inputs = (const float*)d_in[0];   // [B, T, NI]
    const float* H0     = (const float*)d_in[1];   // [B, NH]
    const float* W_xh   = (const float*)d_in[2];   // [NI, NH]
    const float* W_hh   = (const float*)d_in[3];   // [NH, NH]
    const float* b_h    = (const float*)d_in[4];   // [NH]

    float* out = (float*)d_out;                        // outs [B,T,NH]
    float* hT  = out + (size_t)B_SZ * T_SZ * NH;       // H_T [B,NH]

    // 1) input projection -> d_out outs region (in-place scratch)
    dim3 g1(NH / BN, (B_SZ * T_SZ) / BM);  // (8, 4096)
    proj_gemm<<<g1, 256, 0, stream>>>(inputs, W_xh, b_h, out);

    // 2) sequential recurrence, one WG per batch chain
    rnn_scan<<<128, 512, 0, stream>>>(W_hh, H0, out, hT);
}

// Round 2
// 14252.623 us; speedup vs baseline: 1.3823x; 1.3823x over previous
//
#include <hip/hip_runtime.h>
#include <hip/hip_bf16.h>
#include <math.h>

#define B_SZ 128
#define T_SZ 2048
#define NI 512
#define NH 512

// ---------------------------------------------------------------------------
// Kernel 1: x_proj = inputs @ W_xh + b_h, in-place into d_out's outs region.
// ~84% of fp32 VALU roofline -- left unchanged.
// ---------------------------------------------------------------------------
#define BM 64
#define BN 64
#define BK 16

__global__ __launch_bounds__(256) void proj_gemm(
    const float* __restrict__ A,      // inputs [M=B*T, K=NI]
    const float* __restrict__ W,      // W_xh [K, N]
    const float* __restrict__ bias,   // b_h [N]
    float* __restrict__ C)            // d_out outs region [M, N]
{
    __shared__ float As[BK][BM];
    __shared__ float Bs[BK][BN];
    const int m0 = blockIdx.y * BM;
    const int n0 = blockIdx.x * BN;
    const int tid = threadIdx.x;
    const int tx = tid & 15;
    const int ty = tid >> 4;

    const int ar = tid >> 2;
    const int ac = (tid & 3) * 4;
    const int bk = tid >> 4;
    const int bn = (tid & 15) * 4;

    float acc[4][4] = {};

    for (int k0 = 0; k0 < NI; k0 += BK) {
        float4 av = *reinterpret_cast<const float4*>(
            &A[(size_t)(m0 + ar) * NI + k0 + ac]);
        float4 bv = *reinterpret_cast<const float4*>(
            &W[(size_t)(k0 + bk) * NH + n0 + bn]);
        __syncthreads();
        As[ac + 0][ar] = av.x;
        As[ac + 1][ar] = av.y;
        As[ac + 2][ar] = av.z;
        As[ac + 3][ar] = av.w;
        *reinterpret_cast<float4*>(&Bs[bk][bn]) = bv;
        __syncthreads();
        #pragma unroll
        for (int kk = 0; kk < BK; ++kk) {
            float a[4], b[4];
            #pragma unroll
            for (int i = 0; i < 4; ++i) a[i] = As[kk][ty * 4 + i];
            #pragma unroll
            for (int jj = 0; jj < 4; ++jj) b[jj] = Bs[kk][tx * 4 + jj];
            #pragma unroll
            for (int i = 0; i < 4; ++i)
                #pragma unroll
                for (int jj = 0; jj < 4; ++jj)
                    acc[i][jj] = fmaf(a[i], b[jj], acc[i][jj]);
        }
    }

    #pragma unroll
    for (int i = 0; i < 4; ++i) {
        const size_t row = (size_t)(m0 + ty * 4 + i);
        #pragma unroll
        for (int jj = 0; jj < 4; ++jj) {
            const int col = n0 + tx * 4 + jj;
            C[row * NH + col] = acc[i][jj] + bias[col];
        }
    }
}

// ---------------------------------------------------------------------------
// Kernel 2: persistent-weight scan.
// 256 WGs x 512 threads. WG (g,p): chains c0=4g..4g+3, columns j0=64p..64p+63.
// W slice (512x64) lives in VGPRs (64 floats/thread) for the whole kernel.
// Per step: wave ks computes partial dots over k-chunk [64ks,64ks+64) for all
// 4 chains (h broadcast-read from LDS), LDS-reduce over the 8 waves, tanh,
// publish h[t+1] to a parity-selected global buffer, 8-WG release/acquire
// barrier per chain-group, restage h into LDS.
// Parity-0 buffer == d_out's H_T region, so the final state lands for free.
// 90 KB LDS forces 1 WG/CU -> all 256 WGs co-resident, no deadlock.
// ---------------------------------------------------------------------------
#define CPG 4        // chains per group
#define COLS 64      // columns per slice
#define SLICES 8
#define KCH 64       // k-chunk per wave (512/8)

__global__ __launch_bounds__(512) void rnn_scan_p(
    const float* __restrict__ W,     // W_hh [512][512]
    const float* __restrict__ H0,    // [128][512]
    float* __restrict__ out,         // [128][2048][512]: xp on entry -> h
    float* __restrict__ hb0,         // parity-0 h buffer (== d_out hT region)
    float* __restrict__ hb1,         // parity-1 h buffer (in d_ws)
    unsigned int* __restrict__ cnt)  // [32] counters, stride 16 uints (64 B)
{
    __shared__ float h_lds[CPG * NH];          // 8 KB
    __shared__ float red_lds[8][CPG][COLS];    // 8 KB
    __shared__ float lds_pad[18432];           // 72 KB: force 1 WG/CU

    const int tid = threadIdx.x;
    const int bid = blockIdx.x;
    const int g = bid & 31;          // chain-group (same-XCD heuristic)
    const int p = bid >> 5;          // column-slice
    const int c0 = g * CPG;
    const int j0 = p * COLS;

    if (bid == 0x7fffffff) lds_pad[tid] = 1.0f;  // keep LDS allocated

    const int ks = tid >> 6;         // wave id = k-chunk index
    const int j  = tid & 63;         // column within slice

    // --- load W column-slice chunk into registers (once per kernel) ---
    float wr[KCH];
    {
        const float* wp = W + (size_t)(ks * KCH) * NH + j0 + j;
        #pragma unroll
        for (int e = 0; e < KCH; ++e)
            wr[e] = wp[(size_t)e * NH];
    }

    // --- stage h0 from H0 ---
    {
        const int ci = tid >> 7;
        const int kq = tid & 127;
        float4 v = *reinterpret_cast<const float4*>(
            H0 + (size_t)(c0 + ci) * NH + kq * 4);
        *reinterpret_cast<float4*>(h_lds + ci * NH + kq * 4) = v;
    }
    __syncthreads();

    // reduce-phase roles (threads 0..255 active)
    const int rc = tid >> 6;         // chain when < 4
    const int rj = tid & 63;
    float* outrow = out + (size_t)(c0 + (rc & 3)) * T_SZ * NH + j0 + rj;
    float xp_cur = 0.f;
    if (rc < CPG) xp_cur = outrow[0];

    unsigned int* mycnt = cnt + g * 16;

    for (int t = 0; t < T_SZ; ++t) {
        // prefetch next xp (hides HBM latency under the dot phase)
        float xp_next = 0.f;
        if (rc < CPG && t + 1 < T_SZ)
            xp_next = __builtin_nontemporal_load(outrow + (size_t)(t + 1) * NH);

        // --- dot: partials over this wave's k-chunk, all 4 chains ---
        float acc0 = 0.f, acc1 = 0.f, acc2 = 0.f, acc3 = 0.f;
        const float4* hq = reinterpret_cast<const float4*>(h_lds);
        #pragma unroll
        for (int qq = 0; qq < 16; ++qq) {
            const int qi = ks * 16 + qq;
            float4 ha = hq[0 * 128 + qi];   // wave-uniform addr -> broadcast
            float4 hb = hq[1 * 128 + qi];
            float4 hc = hq[2 * 128 + qi];
            float4 hd = hq[3 * 128 + qi];
            const float w0 = wr[qq * 4 + 0], w1 = wr[qq * 4 + 1];
            const float w2 = wr[qq * 4 + 2], w3 = wr[qq * 4 + 3];
            acc0 = fmaf(ha.w, w3, fmaf(ha.z, w2, fmaf(ha.y, w1, fmaf(ha.x, w0, acc0))));
            acc1 = fmaf(hb.w, w3, fmaf(hb.z, w2, fmaf(hb.y, w1, fmaf(hb.x, w0, acc1))));
            acc2 = fmaf(hc.w, w3, fmaf(hc.z, w2, fmaf(hc.y, w1, fmaf(hc.x, w0, acc2))));
            acc3 = fmaf(hd.w, w3, fmaf(hd.z, w2, fmaf(hd.y, w1, fmaf(hd.x, w0, acc3))));
        }
        red_lds[ks][0][j] = acc0;
        red_lds[ks][1][j] = acc1;
        red_lds[ks][2][j] = acc2;
        red_lds[ks][3][j] = acc3;
        __syncthreads();   // s1: partials visible

        // --- reduce + tanh + publish ---
        if (rc < CPG) {
            float s = red_lds[0][rc][rj];
            #pragma unroll
            for (int kk = 1; kk < 8; ++kk) s += red_lds[kk][rc][rj];
            const float hv = tanhf(xp_cur + s);
            __builtin_nontemporal_store(hv, outrow + (size_t)t * NH);  // write-once
            float* hb = (((t + 1) & 1) == 0) ? hb0 : hb1;
            hb[(size_t)(c0 + rc) * NH + j0 + rj] = hv;                 // publish
            xp_cur = xp_next;
        }
        __syncthreads();   // s2: publishes done block-wide before release

        // --- inter-WG barrier (8 slices of this chain-group) ---
        if (tid == 0) {
            __hip_atomic_fetch_add(mycnt, 1u, __ATOMIC_RELEASE,
                                   __HIP_MEMORY_SCOPE_AGENT);
            const unsigned int target = (unsigned int)(SLICES * (t + 1));
            while (__hip_atomic_load(mycnt, __ATOMIC_RELAXED,
                                     __HIP_MEMORY_SCOPE_AGENT) < target)
                __builtin_amdgcn_s_sleep(1);
            (void)__hip_atomic_load(mycnt, __ATOMIC_ACQUIRE,
                                    __HIP_MEMORY_SCOPE_AGENT);
        }
        __syncthreads();   // s3: whole WG released, caches invalidated

        // --- restage h[t+1] into LDS ---
        {
            const float* hb = (((t + 1) & 1) == 0) ? hb0 : hb1;
            const int ci = tid >> 7;
            const int kq = tid & 127;
            float4 v = *reinterpret_cast<const float4*>(
                hb + (size_t)(c0 + ci) * NH + kq * 4);
            *reinterpret_cast<float4*>(h_lds + ci * NH + kq * 4) = v;
        }
        __syncthreads();   // s4: h[t+1] staged before next dot
    }
    // H_T: final publish (t=2047 -> parity 0) already wrote hb0 == hT region.
}

// ---------------------------------------------------------------------------
extern "C" void kernel_launch(void* const* d_in, const int* in_sizes, int n_in,
                              void* d_out, int out_size, void* d_ws, size_t ws_size,
                              hipStream_t stream) {
    const float* inputs = (const float*)d_in[0];   // [B, T, NI]
    const float* H0     = (const float*)d_in[1];   // [B, NH]
    const float* W_xh   = (const float*)d_in[2];   // [NI, NH]
    const float* W_hh   = (const float*)d_in[3];   // [NH, NH]
    const float* b_h    = (const float*)d_in[4];   // [NH]

    float* out = (float*)d_out;                        // outs [B,T,NH]
    float* hT  = out + (size_t)B_SZ * T_SZ * NH;       // H_T [B,NH] == hb0

    unsigned int* cnt = (unsigned int*)d_ws;           // 32 x 64 B counters
    float* hb1 = (float*)((char*)d_ws + 4096);         // 256 KB parity-1 buf

    // zero the barrier counters (graph-capture-safe, on stream)
    hipMemsetAsync(d_ws, 0, 2048, stream);

    // 1) input projection -> d_out outs region
    dim3 g1(NH / BN, (B_SZ * T_SZ) / BM);  // (8, 4096)
    proj_gemm<<<g1, 256, 0, stream>>>(inputs, W_xh, b_h, out);

    // 2) persistent recurrence: 256 WGs (32 chain-groups x 8 column-slices)
    rnn_scan_p<<<256, 512, 0, stream>>>(W_hh, H0, out, hT, hb1, cnt);
}